// Round 15
// baseline (810.434 us; speedup 1.0000x reference)
//
#include <hip/hip_runtime.h>
#include <hip/hip_bf16.h>

typedef __attribute__((ext_vector_type(8))) short short8;
typedef __attribute__((ext_vector_type(4))) float f32x4;

#define GLOAD_LDS16(gp, lp)                                                      \
  __builtin_amdgcn_global_load_lds(                                              \
      (const __attribute__((address_space(1))) void*)(gp),                       \
      (__attribute__((address_space(3))) void*)(lp), 16, 0, 0)

#define SBAR() asm volatile("s_barrier" ::: "memory")
#define VMC(n)                                                                   \
  do {                                                                           \
    asm volatile("s_waitcnt vmcnt(" #n ")" ::: "memory");                        \
    __builtin_amdgcn_sched_barrier(0);                                           \
  } while (0)

__device__ __forceinline__ unsigned short f2bf_rne(float f) {
  union { float f; unsigned int u; } v; v.f = f;
  unsigned int u = v.u;
  u += 0x7fffu + ((u >> 16) & 1u);
  return (unsigned short)(u >> 16);
}

__device__ __forceinline__ short8 pack8(f32x4 a, f32x4 b) {
  short8 o;
  o[0] = (short)f2bf_rne(a[0]); o[1] = (short)f2bf_rne(a[1]);
  o[2] = (short)f2bf_rne(a[2]); o[3] = (short)f2bf_rne(a[3]);
  o[4] = (short)f2bf_rne(b[0]); o[5] = (short)f2bf_rne(b[1]);
  o[6] = (short)f2bf_rne(b[2]); o[7] = (short)f2bf_rne(b[3]);
  return o;
}

// ---------------------------------------------------------------- convert ----
__global__ void cvt_f32_bf16(const float* __restrict__ src,
                             unsigned short* __restrict__ dst, int n8) {
  int i = blockIdx.x * blockDim.x + threadIdx.x;
  int stride = gridDim.x * blockDim.x;
  const f32x4* s4 = (const f32x4*)src;
  short8* d8 = (short8*)dst;
  for (; i < n8; i += stride) {
    d8[i] = pack8(s4[2 * i], s4[2 * i + 1]);
  }
}

// ---- fused: xb = bf16(x);  T = mask*2*(x@A^T);  Wb chunk = bf16(W chunk) ----
__global__ __launch_bounds__(256) void cvt_lora_kernel(
    const float* __restrict__ x,     // [16384][4096] f32
    const float* __restrict__ A,     // [32][4096]    f32
    const float* __restrict__ W,     // [4096][4096]  f32
    const int* __restrict__ offs,    // [4]
    unsigned short* __restrict__ xb, // [16384][4096] bf16 out
    unsigned short* __restrict__ Wb, // [4096][4096]  bf16 out
    unsigned short* __restrict__ T)  // [16384][32]   bf16 out
{
  __shared__ unsigned short xs[32 * 72];
  __shared__ unsigned short as_[32 * 72];
  const int t = threadIdx.x;
  const int m0 = blockIdx.x * 32;
  const int l = t & 63, w = t >> 6;
  const int wr = w >> 1, wc = w & 1;
  const int lr = l & 15, lk = (l >> 4) * 8;
  const int arow = t >> 3, acol = (t & 7) * 8;
  f32x4 acc = {0, 0, 0, 0};
  for (int kt = 0; kt < 64; ++kt) {
    const int kof = kt * 64 + acol;
    const float* px = x + (size_t)(m0 + arow) * 4096 + kof;
    const float* pa = A + (size_t)arow * 4096 + kof;
    short8 s0 = pack8(*(const f32x4*)px, *(const f32x4*)(px + 4));
    short8 sa = pack8(*(const f32x4*)pa, *(const f32x4*)(pa + 4));
    *(short8*)(xb + (size_t)(m0 + arow) * 4096 + kof) = s0;
    __syncthreads();
    *(short8*)&xs[arow * 72 + acol]  = s0;
    *(short8*)&as_[arow * 72 + acol] = sa;
    __syncthreads();
#pragma unroll
    for (int kk = 0; kk < 2; ++kk) {
      short8 a = *(const short8*)&xs[(wr * 16 + lr) * 72 + kk * 32 + lk];
      short8 b = *(const short8*)&as_[(wc * 16 + lr) * 72 + kk * 32 + lk];
      acc = __builtin_amdgcn_mfma_f32_16x16x32_bf16(a, b, acc, 0, 0, 0);
    }
  }
  const int rowb = (l >> 4) * 4;
#pragma unroll
  for (int j = 0; j < 4; ++j) {
    int m = m0 + wr * 16 + rowb + j;
    int bb = m >> 12, s = m & 4095;
    int kcut = offs[bb]; if (kcut > 4096) kcut = 4096;
    bool keep = s >= 4096 - kcut;
    T[(size_t)m * 32 + wc * 16 + lr] = keep ? f2bf_rne(2.0f * acc[j]) : (unsigned short)0;
  }
  const f32x4* s4 = (const f32x4*)W;
  short8* d8 = (short8*)Wb;
  const int base = blockIdx.x * 4096;
#pragma unroll
  for (int q = 0; q < 16; ++q) {
    int idx = base + q * 256 + t;
    d8[idx] = pack8(s4[2 * idx], s4[2 * idx + 1]);
  }
}

// ------------------------------------------------------------- main GEMM -----
// R11 geometry/swizzle for B (256x256 tile, BK=64, 8 waves, 16x16x32 MFMA,
// quarter-wave swizzle -> ZERO conflicts), but A-OPERAND DIRECT FROM GLOBAL
// (AITER flatmm pattern): A-frags are naturally coalesced 16rows x 64B global
// reads (xb L3-resident) loaded to registers via inline-asm
// global_load_dwordx4, two banks alternating even/odd K-tiles, kk via
// offset:64, pointers advance 128B/tile.  LDS holds only B (2 slots x 32KB =
// 64KiB), halving LDS-unit traffic: reads 192->128/CU/K-tile, writes 512->256
// cyc.  MFMA (2486 cyc) is now the long pipe.  Wait discipline: per tile,
// issue order [8xA(t+1), 2xB1(t+1), 2xB0(t+2)]; boundary VMC(2) leaves only
// B0(t+2) in flight (drains A(t+1), B1(t+1), and B0(t+1) staged last tile).
// VMC includes sched_barrier(0) -- required fence for asm-loaded regs (#18).
__global__ __launch_bounds__(512, 2) void gemm_kernel(
    const unsigned short* __restrict__ xb,   // [16384][4096] bf16
    const unsigned short* __restrict__ Wb,   // [4096][4096]  bf16
    const unsigned short* __restrict__ Tm,   // [16384][32]   bf16 (mask+scale)
    const unsigned short* __restrict__ Bwb,  // [4096][32]    bf16
    const float* __restrict__ bias,          // [4096]
    float* __restrict__ out)                 // [16384][4096] f32
{
  constexpr int K = 4096;
  extern __shared__ char smem[];             // 64 KiB: 2 slots x (B0 16K + B1 16K)

  const int bid = blockIdx.x;
  const int swz = (bid & 7) * 128 + (bid >> 3);
  const int m0 = (swz >> 4) * 256;
  const int n0 = (swz & 15) * 256;

  const int t = threadIdx.x;
  const int l = t & 63, w = t >> 6;
  const int wqr = w >> 2;
  const int pr = (w >> 1) & 1;
  const int pc = w & 1;
  const int lr = l & 15, hi = l >> 4;
  const int e0 = (hi ^ (lr & 7)) * 8;        // verified zero-conflict swizzle

  // B staging (swizzled source, linear LDS dest) -- unchanged from R11.
  const int srow = t >> 3;
  const int schunk = ((t & 7) ^ ((t >> 3) & 7)) * 8;
  const unsigned short* pB0 = Wb + (size_t)(n0 + srow) * K + schunk;
  const unsigned short* pB1 = Wb + (size_t)(n0 + 128 + srow) * K + schunk;
  unsigned short* sm = (unsigned short*)smem;
  const int ldst = t * 16;

#define STGB(PTR, SLOT, HALF, KT)                                               \
  do {                                                                          \
    const unsigned short* g_ = (PTR) + (KT) * 64;                               \
    char* d_ = smem + (SLOT) * 32768 + (HALF) * 16384 + ldst;                   \
    GLOAD_LDS16(g_, d_);                                                        \
    GLOAD_LDS16(g_ + (size_t)64 * K, d_ + 8192);                                \
  } while (0)

  // A direct-load state: 4 row pointers (f=0..3), kk via offset imm (64B).
  unsigned long long aad[4];
#pragma unroll
  for (int f = 0; f < 4; ++f)
    aad[f] = (unsigned long long)(xb + (size_t)(m0 + wqr * 128 + pr * 64 + f * 16 + lr) * 4096 + hi * 8);

  short8 ar[2][2][4];   // [bank][kk][f]; bank0 = even K-tiles, bank1 = odd

#define LDA_K0(BANK)                                                            \
  do {                                                                          \
    asm volatile("global_load_dwordx4 %0, %1, off"            : "=v"(ar[BANK][0][0]) : "v"(aad[0])); \
    asm volatile("global_load_dwordx4 %0, %1, off"            : "=v"(ar[BANK][0][1]) : "v"(aad[1])); \
    asm volatile("global_load_dwordx4 %0, %1, off"            : "=v"(ar[BANK][0][2]) : "v"(aad[2])); \
    asm volatile("global_load_dwordx4 %0, %1, off"            : "=v"(ar[BANK][0][3]) : "v"(aad[3])); \
  } while (0)
#define LDA_K1(BANK)                                                            \
  do {                                                                          \
    asm volatile("global_load_dwordx4 %0, %1, off offset:64"  : "=v"(ar[BANK][1][0]) : "v"(aad[0])); \
    asm volatile("global_load_dwordx4 %0, %1, off offset:64"  : "=v"(ar[BANK][1][1]) : "v"(aad[1])); \
    asm volatile("global_load_dwordx4 %0, %1, off offset:64"  : "=v"(ar[BANK][1][2]) : "v"(aad[2])); \
    asm volatile("global_load_dwordx4 %0, %1, off offset:64"  : "=v"(ar[BANK][1][3]) : "v"(aad[3])); \
  } while (0)
#define ADV()                                                                   \
  do { aad[0] += 128; aad[1] += 128; aad[2] += 128; aad[3] += 128; } while (0)

  f32x4 acc[2][4][4];

  // --- LoRA prestep: register-direct (L2-resident), initializes acc ---
  {
    const unsigned short* tp = Tm + (size_t)(m0 + wqr * 128 + pr * 64 + lr) * 32 + hi * 8;
    short8 la[4];
#pragma unroll
    for (int i = 0; i < 4; ++i) la[i] = *(const short8*)(tp + i * 512);
    short8 lb[2][4];
#pragma unroll
    for (int qc = 0; qc < 2; ++qc)
#pragma unroll
      for (int j = 0; j < 4; ++j)
        lb[qc][j] = *(const short8*)(Bwb + (size_t)(n0 + qc * 128 + pc * 64 + j * 16 + lr) * 32 + hi * 8);
#pragma unroll
    for (int qc = 0; qc < 2; ++qc)
#pragma unroll
      for (int i = 0; i < 4; ++i)
#pragma unroll
        for (int j = 0; j < 4; ++j)
          acc[qc][i][j] = __builtin_amdgcn_mfma_f32_16x16x32_bf16(
              la[i], lb[qc][j], (f32x4){0.f, 0.f, 0.f, 0.f}, 0, 0, 0);
  }

  // prologue: A(0) -> bank0; stage s0.B1@0, s0.B0@0, s1.B0@1.
  // Queue: A(0)x8, B1(0)x2, B0(0)x2, B0(1)x2 = 14; VMC(2) leaves B0(1).
  LDA_K0(0); LDA_K1(0); ADV();
  STGB(pB1, 0, 1, 0);
  STGB(pB0, 0, 0, 0);
  STGB(pB0, 1, 0, 1);
  VMC(2);
  SBAR();

  // Phase: read 4 B-frags; issue A-loads / B-stage; barrier; 16 MFMA; wait; barrier.
#define PHASE(SLOT, QC, KK, BANK, ISSUE_STMT, WAIT_STMT)                        \
  {                                                                             \
    const unsigned short* Bh = sm + (SLOT) * 16384 + (QC) * 8192;               \
    const int ek = e0 ^ ((KK) * 32);                                            \
    short8 bfr[4];                                                              \
    _Pragma("unroll")                                                           \
    for (int j_ = 0; j_ < 4; ++j_)                                              \
      bfr[j_] = *(const short8*)(Bh + (pc * 64 + j_ * 16 + lr) * 64 + ek);      \
    ISSUE_STMT;                                                                 \
    SBAR();                                                                     \
    __builtin_amdgcn_s_setprio(1);                                              \
    _Pragma("unroll")                                                           \
    for (int i_ = 0; i_ < 4; ++i_)                                              \
      _Pragma("unroll")                                                         \
      for (int j_ = 0; j_ < 4; ++j_)                                            \
        acc[QC][i_][j_] = __builtin_amdgcn_mfma_f32_16x16x32_bf16(              \
            ar[BANK][KK][i_], bfr[j_], acc[QC][i_][j_], 0, 0, 0);               \
    __builtin_amdgcn_s_setprio(0);                                              \
    WAIT_STMT;                                                                  \
    SBAR();                                                                     \
  }

#define NOP ((void)0)

  // Iteration I: tiles a=2I (slot0, bank0), b=a+1 (slot1, bank1).
  //  P0: A(b) kk0        P1: A(b) kk1 +ADV   P2: stage s1.B1@b    P3: stage s0.B0@a+2, VMC(2)
  //  P4: A(a+2) kk0      P5: A(a+2) kk1 +ADV P6: stage s0.B1@a+2  P7: stage s1.B0@a+3, VMC(2)
  for (int I = 0; I < 31; ++I) {
    const int a = 2 * I;
    PHASE(0, 0, 0, 0, LDA_K0(1), NOP);
    PHASE(0, 1, 0, 0, { LDA_K1(1); ADV(); }, NOP);
    PHASE(0, 0, 1, 0, STGB(pB1, 1, 1, a + 1), NOP);
    PHASE(0, 1, 1, 0, STGB(pB0, 0, 0, a + 2), VMC(2));
    PHASE(1, 0, 0, 1, LDA_K0(0), NOP);
    PHASE(1, 1, 0, 1, { LDA_K1(0); ADV(); }, NOP);
    PHASE(1, 0, 1, 1, STGB(pB1, 0, 1, a + 2), NOP);
    PHASE(1, 1, 1, 1, STGB(pB0, 1, 0, a + 3), VMC(2));
  }
  // tail I=31: a=62,b=63.  A(63) loaded P0-P1; B1(63) staged P2; drain at P3.
  PHASE(0, 0, 0, 0, LDA_K0(1), NOP);
  PHASE(0, 1, 0, 0, LDA_K1(1), NOP);
  PHASE(0, 0, 1, 0, STGB(pB1, 1, 1, 63), NOP);
  PHASE(0, 1, 1, 0, NOP, VMC(0));
  PHASE(1, 0, 0, 1, NOP, NOP);
  PHASE(1, 1, 0, 1, NOP, NOP);
  PHASE(1, 0, 1, 1, NOP, NOP);
  PHASE(1, 1, 1, 1, NOP, NOP);
#undef PHASE
#undef NOP
#undef STGB
#undef LDA_K0
#undef LDA_K1
#undef ADV

  // epilogue: bias + store (C/D map: col=lr -> N, row=hi*4+e -> M)
  float bv[2][4];
#pragma unroll
  for (int qc = 0; qc < 2; ++qc)
#pragma unroll
    for (int j = 0; j < 4; ++j)
      bv[qc][j] = bias[n0 + qc * 128 + pc * 64 + j * 16 + lr];
  const int rowb = hi * 4;
#pragma unroll
  for (int qc = 0; qc < 2; ++qc)
#pragma unroll
    for (int i = 0; i < 4; ++i)
#pragma unroll
      for (int e = 0; e < 4; ++e) {
        int row = m0 + wqr * 128 + pr * 64 + i * 16 + rowb + e;
        float* orow = out + (size_t)row * 4096 + n0 + qc * 128 + pc * 64;
#pragma unroll
        for (int j = 0; j < 4; ++j) orow[j * 16 + lr] = acc[qc][i][j][e] + bv[qc][j];
      }
}

// ----------------------------------------------------------------- launch ----
extern "C" void kernel_launch(void* const* d_in, const int* in_sizes, int n_in,
                              void* d_out, int out_size, void* d_ws, size_t ws_size,
                              hipStream_t stream) {
  const float* x   = (const float*)d_in[0];
  const int* offs  = (const int*)d_in[1];
  const float* W   = (const float*)d_in[2];
  const float* b   = (const float*)d_in[3];
  const float* A   = (const float*)d_in[4];
  const float* Bw  = (const float*)d_in[5];
  float* out = (float*)d_out;

  char* ws = (char*)d_ws;
  unsigned short* xb  = (unsigned short*)ws;                 // 134,217,728 B
  unsigned short* Wb  = (unsigned short*)(ws + 134217728);   //  33,554,432 B
  unsigned short* Bwb = (unsigned short*)(ws + 167772160);   //     262,144 B
  unsigned short* T   = (unsigned short*)(ws + 168034304);   //   1,048,576 B

  hipFuncSetAttribute((const void*)gemm_kernel,
                      hipFuncAttributeMaxDynamicSharedMemorySize, 65536);

  cvt_f32_bf16<<<64, 256, 0, stream>>>(Bw, Bwb, 131072 / 8);
  cvt_lora_kernel<<<512, 256, 0, stream>>>(x, A, W, offs, xb, Wb, T);
  gemm_kernel<<<1024, 512, 65536, stream>>>(xb, Wb, T, Bwb, b, out);
}

// Round 16
// 594.530 us; speedup vs baseline: 1.3632x; 1.3632x over previous
//
#include <hip/hip_runtime.h>
#include <hip/hip_bf16.h>

typedef __attribute__((ext_vector_type(8))) short short8;
typedef __attribute__((ext_vector_type(4))) float f32x4;

#define GLOAD_LDS16(gp, lp)                                                      \
  __builtin_amdgcn_global_load_lds(                                              \
      (const __attribute__((address_space(1))) void*)(gp),                       \
      (__attribute__((address_space(3))) void*)(lp), 16, 0, 0)

#define SBAR() asm volatile("s_barrier" ::: "memory")
#define VMC(n)                                                                   \
  do {                                                                           \
    asm volatile("s_waitcnt vmcnt(" #n ")" ::: "memory");                        \
    __builtin_amdgcn_sched_barrier(0);                                           \
  } while (0)

__device__ __forceinline__ unsigned short f2bf_rne(float f) {
  union { float f; unsigned int u; } v; v.f = f;
  unsigned int u = v.u;
  u += 0x7fffu + ((u >> 16) & 1u);
  return (unsigned short)(u >> 16);
}

__device__ __forceinline__ short8 pack8(f32x4 a, f32x4 b) {
  short8 o;
  o[0] = (short)f2bf_rne(a[0]); o[1] = (short)f2bf_rne(a[1]);
  o[2] = (short)f2bf_rne(a[2]); o[3] = (short)f2bf_rne(a[3]);
  o[4] = (short)f2bf_rne(b[0]); o[5] = (short)f2bf_rne(b[1]);
  o[6] = (short)f2bf_rne(b[2]); o[7] = (short)f2bf_rne(b[3]);
  return o;
}

// ---------------------------------------------------------------- convert ----
__global__ void cvt_f32_bf16(const float* __restrict__ src,
                             unsigned short* __restrict__ dst, int n8) {
  int i = blockIdx.x * blockDim.x + threadIdx.x;
  int stride = gridDim.x * blockDim.x;
  const f32x4* s4 = (const f32x4*)src;
  short8* d8 = (short8*)dst;
  for (; i < n8; i += stride) {
    d8[i] = pack8(s4[2 * i], s4[2 * i + 1]);
  }
}

// ---- fused: xb = bf16(x);  T = mask*2*(x@A^T);  Wb chunk = bf16(W chunk) ----
__global__ __launch_bounds__(256) void cvt_lora_kernel(
    const float* __restrict__ x,     // [16384][4096] f32
    const float* __restrict__ A,     // [32][4096]    f32
    const float* __restrict__ W,     // [4096][4096]  f32
    const int* __restrict__ offs,    // [4]
    unsigned short* __restrict__ xb, // [16384][4096] bf16 out
    unsigned short* __restrict__ Wb, // [4096][4096]  bf16 out
    unsigned short* __restrict__ T)  // [16384][32]   bf16 out
{
  __shared__ unsigned short xs[32 * 72];
  __shared__ unsigned short as_[32 * 72];
  const int t = threadIdx.x;
  const int m0 = blockIdx.x * 32;
  const int l = t & 63, w = t >> 6;
  const int wr = w >> 1, wc = w & 1;
  const int lr = l & 15, lk = (l >> 4) * 8;
  const int arow = t >> 3, acol = (t & 7) * 8;
  f32x4 acc = {0, 0, 0, 0};
  for (int kt = 0; kt < 64; ++kt) {
    const int kof = kt * 64 + acol;
    const float* px = x + (size_t)(m0 + arow) * 4096 + kof;
    const float* pa = A + (size_t)arow * 4096 + kof;
    short8 s0 = pack8(*(const f32x4*)px, *(const f32x4*)(px + 4));
    short8 sa = pack8(*(const f32x4*)pa, *(const f32x4*)(pa + 4));
    *(short8*)(xb + (size_t)(m0 + arow) * 4096 + kof) = s0;
    __syncthreads();
    *(short8*)&xs[arow * 72 + acol]  = s0;
    *(short8*)&as_[arow * 72 + acol] = sa;
    __syncthreads();
#pragma unroll
    for (int kk = 0; kk < 2; ++kk) {
      short8 a = *(const short8*)&xs[(wr * 16 + lr) * 72 + kk * 32 + lk];
      short8 b = *(const short8*)&as_[(wc * 16 + lr) * 72 + kk * 32 + lk];
      acc = __builtin_amdgcn_mfma_f32_16x16x32_bf16(a, b, acc, 0, 0, 0);
    }
  }
  const int rowb = (l >> 4) * 4;
#pragma unroll
  for (int j = 0; j < 4; ++j) {
    int m = m0 + wr * 16 + rowb + j;
    int bb = m >> 12, s = m & 4095;
    int kcut = offs[bb]; if (kcut > 4096) kcut = 4096;
    bool keep = s >= 4096 - kcut;
    T[(size_t)m * 32 + wc * 16 + lr] = keep ? f2bf_rne(2.0f * acc[j]) : (unsigned short)0;
  }
  const f32x4* s4 = (const f32x4*)W;
  short8* d8 = (short8*)Wb;
  const int base = blockIdx.x * 4096;
#pragma unroll
  for (int q = 0; q < 16; ++q) {
    int idx = base + q * 256 + t;
    d8[idx] = pack8(s4[2 * idx], s4[2 * idx + 1]);
  }
}

// ------------------------------------------------------------- main GEMM -----
// R11 geometry (256x256, BK=64, 2 slots, 8 waves, 16x16x32 MFMA, quarter-wave
// swizzle chunk^=(row&7) -> ZERO conflicts, m201 counted waits 2/iter) with
// the m201 SINGLE-BARRIER phase: {ds_reads; stage; [vmcnt]; s_barrier; MFMA}
// and NO trailing barrier -- phase p+1's ds_reads issue right after phase p's
// MFMA cluster, so the LDS pipe runs under the MFMA pipe within each wave
// (the overlap the two-barrier structure provably forbade; m201 measures
// 62.1% MfmaUtil / 1563 TF with this exact skeleton on this chip).
// WAR (single-barrier): P3's stage into in-use s0.B0 issues after barrier_P2,
// i.e. after all waves issued their last s0.B0 reads; those reads complete
// before their own MFMA_P2 (compiler lgkmcnt) and the DMA write returns
// >=200cyc later -- the m201-verified margin.  Residency: VMC(2) at P3/P7
// before the barrier == R11's guarantee, one phase earlier.
__global__ __launch_bounds__(512, 2) void gemm_kernel(
    const unsigned short* __restrict__ xb,   // [16384][4096] bf16
    const unsigned short* __restrict__ Wb,   // [4096][4096]  bf16
    const unsigned short* __restrict__ Tm,   // [16384][32]   bf16 (mask+scale)
    const unsigned short* __restrict__ Bwb,  // [4096][32]    bf16
    const float* __restrict__ bias,          // [4096]
    float* __restrict__ out)                 // [16384][4096] f32
{
  constexpr int K = 4096;
  extern __shared__ char smem[];             // 128 KiB

  const int bid = blockIdx.x;
  const int swz = (bid & 7) * 128 + (bid >> 3);
  const int m0 = (swz >> 4) * 256;
  const int n0 = (swz & 15) * 256;

  const int t = threadIdx.x;
  const int l = t & 63, w = t >> 6;
  const int wqr = w >> 2;
  const int pr = (w >> 1) & 1;
  const int pc = w & 1;
  const int lr = l & 15, hi = l >> 4;
  const int e0 = (hi ^ (lr & 7)) * 8;        // verified zero-conflict swizzle

  const int srow = t >> 3;
  const int schunk = ((t & 7) ^ ((t >> 3) & 7)) * 8;
  const unsigned short* pA0 = xb + (size_t)(m0 + srow) * K + schunk;
  const unsigned short* pA1 = xb + (size_t)(m0 + 128 + srow) * K + schunk;
  const unsigned short* pB0 = Wb + (size_t)(n0 + srow) * K + schunk;
  const unsigned short* pB1 = Wb + (size_t)(n0 + 128 + srow) * K + schunk;
  unsigned short* sm = (unsigned short*)smem;
  const int ldst = t * 16;

#define STG(PTR, SLOT, ISB, HALF, KT)                                           \
  do {                                                                          \
    const unsigned short* g_ = (PTR) + (KT) * 64;                               \
    char* d_ = smem + (SLOT) * 65536 + (ISB) * 32768 + (HALF) * 16384 + ldst;   \
    GLOAD_LDS16(g_, d_);                                                        \
    GLOAD_LDS16(g_ + (size_t)64 * K, d_ + 8192);                                \
  } while (0)

  f32x4 acc[2][4][4];
  short8 afr[4];   // persists across the qc1 phase (A reuse)

  // --- LoRA prestep: register-direct (L2-resident), initializes acc ---
  {
    const unsigned short* tp = Tm + (size_t)(m0 + wqr * 128 + pr * 64 + lr) * 32 + hi * 8;
    short8 la[4];
#pragma unroll
    for (int i = 0; i < 4; ++i) la[i] = *(const short8*)(tp + i * 512);
    short8 lb[2][4];
#pragma unroll
    for (int qc = 0; qc < 2; ++qc)
#pragma unroll
      for (int j = 0; j < 4; ++j)
        lb[qc][j] = *(const short8*)(Bwb + (size_t)(n0 + qc * 128 + pc * 64 + j * 16 + lr) * 32 + hi * 8);
#pragma unroll
    for (int qc = 0; qc < 2; ++qc)
#pragma unroll
      for (int i = 0; i < 4; ++i)
#pragma unroll
        for (int j = 0; j < 4; ++j)
          acc[qc][i][j] = __builtin_amdgcn_mfma_f32_16x16x32_bf16(
              la[i], lb[qc][j], (f32x4){0.f, 0.f, 0.f, 0.f}, 0, 0, 0);
  }

  // prologue: tile0 all 4 halves + s1.B0@1; VMC(2) leaves s1.B0 in flight.
  STG(pB1, 0, 1, 1, 0);
  STG(pA0, 0, 0, 0, 0);
  STG(pA1, 0, 0, 1, 0);
  STG(pB0, 0, 1, 0, 0);
  STG(pB0, 1, 1, 0, 1);
  VMC(2);
  SBAR();

  // m201-style phase: reads -> stage -> [wait] -> ONE barrier -> MFMA.
#define PHASE(SLOT, QC, KK, READA, STG_STMT, WAIT_STMT)                         \
  {                                                                             \
    const unsigned short* Ah = sm + (SLOT) * 32768 + wqr * 8192;                \
    const unsigned short* Bh = sm + (SLOT) * 32768 + 16384 + (QC) * 8192;       \
    const int ek = e0 ^ ((KK) * 32);                                            \
    if (READA) {                                                                \
      _Pragma("unroll")                                                         \
      for (int i = 0; i < 4; ++i)                                               \
        afr[i] = *(const short8*)(Ah + (pr * 64 + i * 16 + lr) * 64 + ek);      \
    }                                                                           \
    short8 bfr[4];                                                              \
    _Pragma("unroll")                                                           \
    for (int j = 0; j < 4; ++j)                                                 \
      bfr[j] = *(const short8*)(Bh + (pc * 64 + j * 16 + lr) * 64 + ek);        \
    STG_STMT;                                                                   \
    WAIT_STMT;                                                                  \
    SBAR();                                                                     \
    __builtin_amdgcn_s_setprio(1);                                              \
    _Pragma("unroll")                                                           \
    for (int i = 0; i < 4; ++i)                                                 \
      _Pragma("unroll")                                                         \
      for (int j = 0; j < 4; ++j)                                               \
        acc[QC][i][j] = __builtin_amdgcn_mfma_f32_16x16x32_bf16(                \
            afr[i], bfr[j], acc[QC][i][j], 0, 0, 0);                            \
    __builtin_amdgcn_s_setprio(0);                                              \
  }

  // stage stream identical to R11; VMC(2) only at P3/P7 (pre-barrier).
  for (int I = 0; I < 31; ++I) {
    const int a = 2 * I;
    PHASE(0, 0, 0, 1, STG(pB1, 1, 1, 1, a + 1), ((void)0));
    PHASE(0, 1, 0, 0, STG(pA0, 1, 0, 0, a + 1), ((void)0));
    PHASE(0, 0, 1, 1, STG(pA1, 1, 0, 1, a + 1), ((void)0));
    PHASE(0, 1, 1, 0, STG(pB0, 0, 1, 0, a + 2), VMC(2));
    PHASE(1, 0, 0, 1, STG(pB1, 0, 1, 1, a + 2), ((void)0));
    PHASE(1, 1, 0, 0, STG(pA0, 0, 0, 0, a + 2), ((void)0));
    PHASE(1, 0, 1, 1, STG(pA1, 0, 0, 1, a + 2), ((void)0));
    PHASE(1, 1, 1, 0, STG(pB0, 1, 1, 0, a + 3), VMC(2));
  }
  // tail: slot0 = tile 62; stage tile 63's B1/A0/A1; drain VMC(0) at P3.
  PHASE(0, 0, 0, 1, STG(pB1, 1, 1, 1, 63), ((void)0));
  PHASE(0, 1, 0, 0, STG(pA0, 1, 0, 0, 63), ((void)0));
  PHASE(0, 0, 1, 1, STG(pA1, 1, 0, 1, 63), ((void)0));
  PHASE(0, 1, 1, 0, ((void)0), VMC(0));
  PHASE(1, 0, 0, 1, ((void)0), ((void)0));
  PHASE(1, 1, 0, 0, ((void)0), ((void)0));
  PHASE(1, 0, 1, 1, ((void)0), ((void)0));
  PHASE(1, 1, 1, 0, ((void)0), ((void)0));
#undef PHASE
#undef STG

  // epilogue: bias + store (C/D map: col=lr -> N, row=hi*4+e -> M).
  // No LDS use here -> no barrier needed after the last MFMA phase.
  float bv[2][4];
#pragma unroll
  for (int qc = 0; qc < 2; ++qc)
#pragma unroll
    for (int j = 0; j < 4; ++j)
      bv[qc][j] = bias[n0 + qc * 128 + pc * 64 + j * 16 + lr];
  const int rowb = hi * 4;
#pragma unroll
  for (int qc = 0; qc < 2; ++qc)
#pragma unroll
    for (int i = 0; i < 4; ++i)
#pragma unroll
      for (int e = 0; e < 4; ++e) {
        int row = m0 + wqr * 128 + pr * 64 + i * 16 + rowb + e;
        float* orow = out + (size_t)row * 4096 + n0 + qc * 128 + pc * 64;
#pragma unroll
        for (int j = 0; j < 4; ++j) orow[j * 16 + lr] = acc[qc][i][j][e] + bv[qc][j];
      }
}

// ----------------------------------------------------------------- launch ----
extern "C" void kernel_launch(void* const* d_in, const int* in_sizes, int n_in,
                              void* d_out, int out_size, void* d_ws, size_t ws_size,
                              hipStream_t stream) {
  const float* x   = (const float*)d_in[0];
  const int* offs  = (const int*)d_in[1];
  const float* W   = (const float*)d_in[2];
  const float* b   = (const float*)d_in[3];
  const float* A   = (const float*)d_in[4];
  const float* Bw  = (const float*)d_in[5];
  float* out = (float*)d_out;

  char* ws = (char*)d_ws;
  unsigned short* xb  = (unsigned short*)ws;                 // 134,217,728 B
  unsigned short* Wb  = (unsigned short*)(ws + 134217728);   //  33,554,432 B
  unsigned short* Bwb = (unsigned short*)(ws + 167772160);   //     262,144 B
  unsigned short* T   = (unsigned short*)(ws + 168034304);   //   1,048,576 B

  hipFuncSetAttribute((const void*)gemm_kernel,
                      hipFuncAttributeMaxDynamicSharedMemorySize, 131072);

  cvt_f32_bf16<<<64, 256, 0, stream>>>(Bw, Bwb, 131072 / 8);
  cvt_lora_kernel<<<512, 256, 0, stream>>>(x, A, W, offs, xb, Wb, T);
  gemm_kernel<<<1024, 512, 131072, stream>>>(xb, Wb, T, Bwb, b, out);
}

// Round 17
// 583.763 us; speedup vs baseline: 1.3883x; 1.0184x over previous
//
#include <hip/hip_runtime.h>
#include <hip/hip_bf16.h>

typedef __attribute__((ext_vector_type(8))) short short8;
typedef __attribute__((ext_vector_type(4))) float f32x4;

#define GLOAD_LDS16(gp, lp)                                                      \
  __builtin_amdgcn_global_load_lds(                                              \
      (const __attribute__((address_space(1))) void*)(gp),                       \
      (__attribute__((address_space(3))) void*)(lp), 16, 0, 0)

#define SBAR() asm volatile("s_barrier" ::: "memory")
#define VMC(n)                                                                   \
  do {                                                                           \
    asm volatile("s_waitcnt vmcnt(" #n ")" ::: "memory");                        \
    __builtin_amdgcn_sched_barrier(0);                                           \
  } while (0)

__device__ __forceinline__ unsigned short f2bf_rne(float f) {
  union { float f; unsigned int u; } v; v.f = f;
  unsigned int u = v.u;
  u += 0x7fffu + ((u >> 16) & 1u);
  return (unsigned short)(u >> 16);
}

__device__ __forceinline__ short8 pack8(f32x4 a, f32x4 b) {
  short8 o;
  o[0] = (short)f2bf_rne(a[0]); o[1] = (short)f2bf_rne(a[1]);
  o[2] = (short)f2bf_rne(a[2]); o[3] = (short)f2bf_rne(a[3]);
  o[4] = (short)f2bf_rne(b[0]); o[5] = (short)f2bf_rne(b[1]);
  o[6] = (short)f2bf_rne(b[2]); o[7] = (short)f2bf_rne(b[3]);
  return o;
}

// ---- fused prep: xb = bf16(x); T = mask*2*(x@A^T); Wb = bf16(W);
//      Bwb = bf16(Bw) (blocks < 64) ----
// Register double-buffer prefetch: iter k+1's f32 loads issue before iter k's
// first barrier, hiding HBM latency under the MFMA + sync chain.
__global__ __launch_bounds__(256) void cvt_lora_kernel(
    const float* __restrict__ x,     // [16384][4096] f32
    const float* __restrict__ A,     // [32][4096]    f32
    const float* __restrict__ W,     // [4096][4096]  f32
    const float* __restrict__ Bw,    // [4096][32]    f32
    const int* __restrict__ offs,    // [4]
    unsigned short* __restrict__ xb, // [16384][4096] bf16 out
    unsigned short* __restrict__ Wb, // [4096][4096]  bf16 out
    unsigned short* __restrict__ Bwb,// [4096][32]    bf16 out
    unsigned short* __restrict__ T)  // [16384][32]   bf16 out
{
  __shared__ unsigned short xs[32 * 72];
  __shared__ unsigned short as_[32 * 72];
  const int t = threadIdx.x;
  const int m0 = blockIdx.x * 32;
  const int l = t & 63, w = t >> 6;
  const int wr = w >> 1, wc = w & 1;
  const int lr = l & 15, lk = (l >> 4) * 8;
  const int arow = t >> 3, acol = (t & 7) * 8;

  // Bw conversion: blocks 0..63, one short8 per thread (16384 total)
  if (blockIdx.x < 64) {
    int idx = blockIdx.x * 256 + t;
    const f32x4* s4b = (const f32x4*)Bw;
    ((short8*)Bwb)[idx] = pack8(s4b[2 * idx], s4b[2 * idx + 1]);
  }

  const float* px = x + (size_t)(m0 + arow) * 4096 + acol;
  const float* pa = A + (size_t)arow * 4096 + acol;
  f32x4 vx0 = *(const f32x4*)px, vx1 = *(const f32x4*)(px + 4);
  f32x4 va0 = *(const f32x4*)pa, va1 = *(const f32x4*)(pa + 4);

  f32x4 acc = {0, 0, 0, 0};
  for (int kt = 0; kt < 64; ++kt) {
    short8 s0 = pack8(vx0, vx1);
    short8 sa = pack8(va0, va1);
    if (kt < 63) {                        // prefetch next iteration
      px += 64; pa += 64;
      vx0 = *(const f32x4*)px; vx1 = *(const f32x4*)(px + 4);
      va0 = *(const f32x4*)pa; va1 = *(const f32x4*)(pa + 4);
    }
    *(short8*)(xb + (size_t)(m0 + arow) * 4096 + kt * 64 + acol) = s0;
    __syncthreads();                      // prior-iter LDS reads complete
    *(short8*)&xs[arow * 72 + acol]  = s0;
    *(short8*)&as_[arow * 72 + acol] = sa;
    __syncthreads();
#pragma unroll
    for (int kk = 0; kk < 2; ++kk) {
      short8 a = *(const short8*)&xs[(wr * 16 + lr) * 72 + kk * 32 + lk];
      short8 b = *(const short8*)&as_[(wc * 16 + lr) * 72 + kk * 32 + lk];
      acc = __builtin_amdgcn_mfma_f32_16x16x32_bf16(a, b, acc, 0, 0, 0);
    }
  }
  const int rowb = (l >> 4) * 4;
#pragma unroll
  for (int j = 0; j < 4; ++j) {
    int m = m0 + wr * 16 + rowb + j;
    int bb = m >> 12, s = m & 4095;
    int kcut = offs[bb]; if (kcut > 4096) kcut = 4096;
    bool keep = s >= 4096 - kcut;
    T[(size_t)m * 32 + wc * 16 + lr] = keep ? f2bf_rne(2.0f * acc[j]) : (unsigned short)0;
  }
  // W conversion tail: 1/512 of W per block
  const f32x4* s4 = (const f32x4*)W;
  short8* d8 = (short8*)Wb;
  const int base = blockIdx.x * 4096;
#pragma unroll
  for (int q = 0; q < 16; ++q) {
    int idx = base + q * 256 + t;
    d8[idx] = pack8(s4[2 * idx], s4[2 * idx + 1]);
  }
}

// ------------------------------------------------------------- main GEMM -----
// R13/R11 structure (best measured: 256x256 tile, BK=64, 2 slots, 8 waves,
// 16x16x32 MFMA, quarter-wave swizzle chunk^=(row&7) -> ZERO bank conflicts,
// m201 counted waits 2/iter, two-barrier phase).  Only change vs R13:
// s_setprio removed -- phase-locked waves give it nothing to arbitrate
// (T5 prerequisite absent; m190 measured it as a small net cost here).
__global__ __launch_bounds__(512, 2) void gemm_kernel(
    const unsigned short* __restrict__ xb,   // [16384][4096] bf16
    const unsigned short* __restrict__ Wb,   // [4096][4096]  bf16
    const unsigned short* __restrict__ Tm,   // [16384][32]   bf16 (mask+scale)
    const unsigned short* __restrict__ Bwb,  // [4096][32]    bf16
    const float* __restrict__ bias,          // [4096]
    float* __restrict__ out)                 // [16384][4096] f32
{
  constexpr int K = 4096;
  extern __shared__ char smem[];             // 128 KiB

  const int bid = blockIdx.x;
  const int swz = (bid & 7) * 128 + (bid >> 3);
  const int m0 = (swz >> 4) * 256;
  const int n0 = (swz & 15) * 256;

  const int t = threadIdx.x;
  const int l = t & 63, w = t >> 6;
  const int wqr = w >> 2;
  const int pr = (w >> 1) & 1;
  const int pc = w & 1;
  const int lr = l & 15, hi = l >> 4;
  const int e0 = (hi ^ (lr & 7)) * 8;        // verified zero-conflict swizzle

  const int srow = t >> 3;
  const int schunk = ((t & 7) ^ ((t >> 3) & 7)) * 8;
  const unsigned short* pA0 = xb + (size_t)(m0 + srow) * K + schunk;
  const unsigned short* pA1 = xb + (size_t)(m0 + 128 + srow) * K + schunk;
  const unsigned short* pB0 = Wb + (size_t)(n0 + srow) * K + schunk;
  const unsigned short* pB1 = Wb + (size_t)(n0 + 128 + srow) * K + schunk;
  unsigned short* sm = (unsigned short*)smem;
  const int ldst = t * 16;

#define STG(PTR, SLOT, ISB, HALF, KT)                                           \
  do {                                                                          \
    const unsigned short* g_ = (PTR) + (KT) * 64;                               \
    char* d_ = smem + (SLOT) * 65536 + (ISB) * 32768 + (HALF) * 16384 + ldst;   \
    GLOAD_LDS16(g_, d_);                                                        \
    GLOAD_LDS16(g_ + (size_t)64 * K, d_ + 8192);                                \
  } while (0)

  f32x4 acc[2][4][4];
  short8 afr[4];   // persists across the qc1 phase (A reuse)

  // --- LoRA prestep: register-direct (L2-resident), initializes acc ---
  {
    const unsigned short* tp = Tm + (size_t)(m0 + wqr * 128 + pr * 64 + lr) * 32 + hi * 8;
    short8 la[4];
#pragma unroll
    for (int i = 0; i < 4; ++i) la[i] = *(const short8*)(tp + i * 512);
    short8 lb[2][4];
#pragma unroll
    for (int qc = 0; qc < 2; ++qc)
#pragma unroll
      for (int j = 0; j < 4; ++j)
        lb[qc][j] = *(const short8*)(Bwb + (size_t)(n0 + qc * 128 + pc * 64 + j * 16 + lr) * 32 + hi * 8);
#pragma unroll
    for (int qc = 0; qc < 2; ++qc)
#pragma unroll
      for (int i = 0; i < 4; ++i)
#pragma unroll
        for (int j = 0; j < 4; ++j)
          acc[qc][i][j] = __builtin_amdgcn_mfma_f32_16x16x32_bf16(
              la[i], lb[qc][j], (f32x4){0.f, 0.f, 0.f, 0.f}, 0, 0, 0);
  }

  // prologue: tile0 all 4 halves + s1.B0@1; VMC(2) leaves s1.B0 in flight.
  STG(pB1, 0, 1, 1, 0);
  STG(pA0, 0, 0, 0, 0);
  STG(pA1, 0, 0, 1, 0);
  STG(pB0, 0, 1, 0, 0);
  STG(pB0, 1, 1, 0, 1);
  VMC(2);
  SBAR();

#define PHASE(SLOT, QC, KK, READA, STG_STMT, WAIT_STMT)                         \
  {                                                                             \
    const unsigned short* Ah = sm + (SLOT) * 32768 + wqr * 8192;                \
    const unsigned short* Bh = sm + (SLOT) * 32768 + 16384 + (QC) * 8192;       \
    const int ek = e0 ^ ((KK) * 32);                                            \
    if (READA) {                                                                \
      _Pragma("unroll")                                                         \
      for (int i = 0; i < 4; ++i)                                               \
        afr[i] = *(const short8*)(Ah + (pr * 64 + i * 16 + lr) * 64 + ek);      \
    }                                                                           \
    short8 bfr[4];                                                              \
    _Pragma("unroll")                                                           \
    for (int j = 0; j < 4; ++j)                                                 \
      bfr[j] = *(const short8*)(Bh + (pc * 64 + j * 16 + lr) * 64 + ek);        \
    STG_STMT;                                                                   \
    SBAR();                                                                     \
    _Pragma("unroll")                                                           \
    for (int i = 0; i < 4; ++i)                                                 \
      _Pragma("unroll")                                                         \
      for (int j = 0; j < 4; ++j)                                               \
        acc[QC][i][j] = __builtin_amdgcn_mfma_f32_16x16x32_bf16(                \
            afr[i], bfr[j], acc[QC][i][j], 0, 0, 0);                            \
    WAIT_STMT;                                                                  \
    SBAR();                                                                     \
  }

  for (int I = 0; I < 31; ++I) {
    const int a = 2 * I;
    PHASE(0, 0, 0, 1, STG(pB1, 1, 1, 1, a + 1), ((void)0));
    PHASE(0, 1, 0, 0, STG(pA0, 1, 0, 0, a + 1), ((void)0));
    PHASE(0, 0, 1, 1, STG(pA1, 1, 0, 1, a + 1), ((void)0));
    PHASE(0, 1, 1, 0, STG(pB0, 0, 1, 0, a + 2), VMC(2));
    PHASE(1, 0, 0, 1, STG(pB1, 0, 1, 1, a + 2), ((void)0));
    PHASE(1, 1, 0, 0, STG(pA0, 0, 0, 0, a + 2), ((void)0));
    PHASE(1, 0, 1, 1, STG(pA1, 0, 0, 1, a + 2), ((void)0));
    PHASE(1, 1, 1, 0, STG(pB0, 1, 1, 0, a + 3), VMC(2));
  }
  // tail: slot0 = tile 62; stage tile 63's B1/A0/A1; drain VMC(0).
  PHASE(0, 0, 0, 1, STG(pB1, 1, 1, 1, 63), ((void)0));
  PHASE(0, 1, 0, 0, STG(pA0, 1, 0, 0, 63), ((void)0));
  PHASE(0, 0, 1, 1, STG(pA1, 1, 0, 1, 63), ((void)0));
  PHASE(0, 1, 1, 0, ((void)0), VMC(0));
  PHASE(1, 0, 0, 1, ((void)0), ((void)0));
  PHASE(1, 1, 0, 0, ((void)0), ((void)0));
  PHASE(1, 0, 1, 1, ((void)0), ((void)0));
  PHASE(1, 1, 1, 0, ((void)0), ((void)0));
#undef PHASE
#undef STG

  // epilogue: bias + store (C/D map: col=lr -> N, row=hi*4+e -> M)
  float bv[2][4];
#pragma unroll
  for (int qc = 0; qc < 2; ++qc)
#pragma unroll
    for (int j = 0; j < 4; ++j)
      bv[qc][j] = bias[n0 + qc * 128 + pc * 64 + j * 16 + lr];
  const int rowb = hi * 4;
#pragma unroll
  for (int qc = 0; qc < 2; ++qc)
#pragma unroll
    for (int i = 0; i < 4; ++i)
#pragma unroll
      for (int e = 0; e < 4; ++e) {
        int row = m0 + wqr * 128 + pr * 64 + i * 16 + rowb + e;
        float* orow = out + (size_t)row * 4096 + n0 + qc * 128 + pc * 64;
#pragma unroll
        for (int j = 0; j < 4; ++j) orow[j * 16 + lr] = acc[qc][i][j][e] + bv[qc][j];
      }
}

// ----------------------------------------------------------------- launch ----
extern "C" void kernel_launch(void* const* d_in, const int* in_sizes, int n_in,
                              void* d_out, int out_size, void* d_ws, size_t ws_size,
                              hipStream_t stream) {
  const float* x   = (const float*)d_in[0];
  const int* offs  = (const int*)d_in[1];
  const float* W   = (const float*)d_in[2];
  const float* b   = (const float*)d_in[3];
  const float* A   = (const float*)d_in[4];
  const float* Bw  = (const float*)d_in[5];
  float* out = (float*)d_out;

  char* ws = (char*)d_ws;
  unsigned short* xb  = (unsigned short*)ws;                 // 134,217,728 B
  unsigned short* Wb  = (unsigned short*)(ws + 134217728);   //  33,554,432 B
  unsigned short* Bwb = (unsigned short*)(ws + 167772160);   //     262,144 B
  unsigned short* T   = (unsigned short*)(ws + 168034304);   //   1,048,576 B

  hipFuncSetAttribute((const void*)gemm_kernel,
                      hipFuncAttributeMaxDynamicSharedMemorySize, 131072);

  cvt_lora_kernel<<<512, 256, 0, stream>>>(x, A, W, Bw, offs, xb, Wb, Bwb, T);
  gemm_kernel<<<1024, 512, 131072, stream>>>(xb, Wb, T, Bwb, b, out);
}

// Round 18
// 565.412 us; speedup vs baseline: 1.4334x; 1.0325x over previous
//
#include <hip/hip_runtime.h>
#include <hip/hip_bf16.h>

typedef __attribute__((ext_vector_type(8))) short short8;
typedef __attribute__((ext_vector_type(4))) float f32x4;

#define GLOAD_LDS16(gp, lp)                                                      \
  __builtin_amdgcn_global_load_lds(                                              \
      (const __attribute__((address_space(1))) void*)(gp),                       \
      (__attribute__((address_space(3))) void*)(lp), 16, 0, 0)

#define SBAR() asm volatile("s_barrier" ::: "memory")
#define VMC(n)                                                                   \
  do {                                                                           \
    asm volatile("s_waitcnt vmcnt(" #n ")" ::: "memory");                        \
    __builtin_amdgcn_sched_barrier(0);                                           \
  } while (0)

__device__ __forceinline__ unsigned short f2bf_rne(float f) {
  union { float f; unsigned int u; } v; v.f = f;
  unsigned int u = v.u;
  u += 0x7fffu + ((u >> 16) & 1u);
  return (unsigned short)(u >> 16);
}

__device__ __forceinline__ short8 pack8(f32x4 a, f32x4 b) {
  short8 o;
  o[0] = (short)f2bf_rne(a[0]); o[1] = (short)f2bf_rne(a[1]);
  o[2] = (short)f2bf_rne(a[2]); o[3] = (short)f2bf_rne(a[3]);
  o[4] = (short)f2bf_rne(b[0]); o[5] = (short)f2bf_rne(b[1]);
  o[6] = (short)f2bf_rne(b[2]); o[7] = (short)f2bf_rne(b[3]);
  return o;
}

// ---- fused prep: xb = bf16(x); T = mask*2*(x@A^T); Wb = bf16(W);
//      Bwb = bf16(Bw) (blocks < 64) ----
__global__ __launch_bounds__(256) void cvt_lora_kernel(
    const float* __restrict__ x,     // [16384][4096] f32
    const float* __restrict__ A,     // [32][4096]    f32
    const float* __restrict__ W,     // [4096][4096]  f32
    const float* __restrict__ Bw,    // [4096][32]    f32
    const int* __restrict__ offs,    // [4]
    unsigned short* __restrict__ xb, // [16384][4096] bf16 out
    unsigned short* __restrict__ Wb, // [4096][4096]  bf16 out
    unsigned short* __restrict__ Bwb,// [4096][32]    bf16 out
    unsigned short* __restrict__ T)  // [16384][32]   bf16 out
{
  __shared__ unsigned short xs[32 * 72];
  __shared__ unsigned short as_[32 * 72];
  const int t = threadIdx.x;
  const int m0 = blockIdx.x * 32;
  const int l = t & 63, w = t >> 6;
  const int wr = w >> 1, wc = w & 1;
  const int lr = l & 15, lk = (l >> 4) * 8;
  const int arow = t >> 3, acol = (t & 7) * 8;

  if (blockIdx.x < 64) {
    int idx = blockIdx.x * 256 + t;
    const f32x4* s4b = (const f32x4*)Bw;
    ((short8*)Bwb)[idx] = pack8(s4b[2 * idx], s4b[2 * idx + 1]);
  }

  const float* px = x + (size_t)(m0 + arow) * 4096 + acol;
  const float* pa = A + (size_t)arow * 4096 + acol;
  f32x4 vx0 = *(const f32x4*)px, vx1 = *(const f32x4*)(px + 4);
  f32x4 va0 = *(const f32x4*)pa, va1 = *(const f32x4*)(pa + 4);

  f32x4 acc = {0, 0, 0, 0};
  for (int kt = 0; kt < 64; ++kt) {
    short8 s0 = pack8(vx0, vx1);
    short8 sa = pack8(va0, va1);
    if (kt < 63) {                        // prefetch next iteration
      px += 64; pa += 64;
      vx0 = *(const f32x4*)px; vx1 = *(const f32x4*)(px + 4);
      va0 = *(const f32x4*)pa; va1 = *(const f32x4*)(pa + 4);
    }
    *(short8*)(xb + (size_t)(m0 + arow) * 4096 + kt * 64 + acol) = s0;
    __syncthreads();
    *(short8*)&xs[arow * 72 + acol]  = s0;
    *(short8*)&as_[arow * 72 + acol] = sa;
    __syncthreads();
#pragma unroll
    for (int kk = 0; kk < 2; ++kk) {
      short8 a = *(const short8*)&xs[(wr * 16 + lr) * 72 + kk * 32 + lk];
      short8 b = *(const short8*)&as_[(wc * 16 + lr) * 72 + kk * 32 + lk];
      acc = __builtin_amdgcn_mfma_f32_16x16x32_bf16(a, b, acc, 0, 0, 0);
    }
  }
  const int rowb = (l >> 4) * 4;
#pragma unroll
  for (int j = 0; j < 4; ++j) {
    int m = m0 + wr * 16 + rowb + j;
    int bb = m >> 12, s = m & 4095;
    int kcut = offs[bb]; if (kcut > 4096) kcut = 4096;
    bool keep = s >= 4096 - kcut;
    T[(size_t)m * 32 + wc * 16 + lr] = keep ? f2bf_rne(2.0f * acc[j]) : (unsigned short)0;
  }
  const f32x4* s4 = (const f32x4*)W;
  short8* d8 = (short8*)Wb;
  const int base = blockIdx.x * 4096;
#pragma unroll
  for (int q = 0; q < 16; ++q) {
    int idx = base + q * 256 + t;
    d8[idx] = pack8(s4[2 * idx], s4[2 * idx + 1]);
  }
}

// ------------------------------------------------------------- main GEMM -----
// R13 structure (256x256, BK=64, 2 slots, 8 waves, 16x16x32 MFMA, quarter-wave
// swizzle chunk^=(row&7) -> ZERO conflicts, setprio) with m201's LOOSE wait
// discipline: one half staged per phase in order [s1.A1, s1.B0, s1.B1, s0.A0 |
// s0.A1, s0.B0, s0.B1, s1.A0]; VMC(4) at P0/P3/P4/P7.  Every forced load is
// >=3-4 phases old (vs R13's 1 phase), in-flight depth 4 loads throughout.
// Residency audit (VMC(4) leaves newest 2 halves):
//  endP7(I-1) forces P3/P4/P5 stages = s0.A0,A1,B0@a -> P0 reads OK
//  endP0 forces P6(I-1) = s0.B1@a -> P1 OK
//  endP3 forces P7(I-1),P0,P1 = s1.A0,A1,B0@a+1 -> P4 OK
//  endP4 forces P2 = s1.B1@a+1 -> P5 OK
// WAR: each stage >= 1 phase (2 barriers) after its region's last read issue
// (s0.A last read P2 -> staged P3+; s0.B0 P2 -> P5; s0.B1 P3 -> P6;
//  s1.A P6 -> P7/P0; s1.B0 P6 -> P1'; s1.B1 P7 -> P2').
__global__ __launch_bounds__(512, 2) void gemm_kernel(
    const unsigned short* __restrict__ xb,   // [16384][4096] bf16
    const unsigned short* __restrict__ Wb,   // [4096][4096]  bf16
    const unsigned short* __restrict__ Tm,   // [16384][32]   bf16 (mask+scale)
    const unsigned short* __restrict__ Bwb,  // [4096][32]    bf16
    const float* __restrict__ bias,          // [4096]
    float* __restrict__ out)                 // [16384][4096] f32
{
  constexpr int K = 4096;
  extern __shared__ char smem[];             // 128 KiB

  const int bid = blockIdx.x;
  const int swz = (bid & 7) * 128 + (bid >> 3);
  const int m0 = (swz >> 4) * 256;
  const int n0 = (swz & 15) * 256;

  const int t = threadIdx.x;
  const int l = t & 63, w = t >> 6;
  const int wqr = w >> 2;
  const int pr = (w >> 1) & 1;
  const int pc = w & 1;
  const int lr = l & 15, hi = l >> 4;
  const int e0 = (hi ^ (lr & 7)) * 8;        // verified zero-conflict swizzle

  const int srow = t >> 3;
  const int schunk = ((t & 7) ^ ((t >> 3) & 7)) * 8;
  const unsigned short* pA0 = xb + (size_t)(m0 + srow) * K + schunk;
  const unsigned short* pA1 = xb + (size_t)(m0 + 128 + srow) * K + schunk;
  const unsigned short* pB0 = Wb + (size_t)(n0 + srow) * K + schunk;
  const unsigned short* pB1 = Wb + (size_t)(n0 + 128 + srow) * K + schunk;
  unsigned short* sm = (unsigned short*)smem;
  const int ldst = t * 16;

#define STG(PTR, SLOT, ISB, HALF, KT)                                           \
  do {                                                                          \
    const unsigned short* g_ = (PTR) + (KT) * 64;                               \
    char* d_ = smem + (SLOT) * 65536 + (ISB) * 32768 + (HALF) * 16384 + ldst;   \
    GLOAD_LDS16(g_, d_);                                                        \
    GLOAD_LDS16(g_ + (size_t)64 * K, d_ + 8192);                                \
  } while (0)

  f32x4 acc[2][4][4];
  short8 afr[4];   // persists across the qc1 phase (A reuse)

  // --- LoRA prestep: register-direct (L2-resident), initializes acc ---
  {
    const unsigned short* tp = Tm + (size_t)(m0 + wqr * 128 + pr * 64 + lr) * 32 + hi * 8;
    short8 la[4];
#pragma unroll
    for (int i = 0; i < 4; ++i) la[i] = *(const short8*)(tp + i * 512);
    short8 lb[2][4];
#pragma unroll
    for (int qc = 0; qc < 2; ++qc)
#pragma unroll
      for (int j = 0; j < 4; ++j)
        lb[qc][j] = *(const short8*)(Bwb + (size_t)(n0 + qc * 128 + pc * 64 + j * 16 + lr) * 32 + hi * 8);
#pragma unroll
    for (int qc = 0; qc < 2; ++qc)
#pragma unroll
      for (int i = 0; i < 4; ++i)
#pragma unroll
        for (int j = 0; j < 4; ++j)
          acc[qc][i][j] = __builtin_amdgcn_mfma_f32_16x16x32_bf16(
              la[i], lb[qc][j], (f32x4){0.f, 0.f, 0.f, 0.f}, 0, 0, 0);
  }

  // prologue: s0 all 4 halves @0 (oldest first), s1.A0@1; VMC(4) leaves
  // {s0.B1@0, s1.A0@1} in flight, forces s0.A0/A1/B0 for P0.
  STG(pA0, 0, 0, 0, 0);
  STG(pA1, 0, 0, 1, 0);
  STG(pB0, 0, 1, 0, 0);
  STG(pB1, 0, 1, 1, 0);
  STG(pA0, 1, 0, 0, 1);
  VMC(4);
  SBAR();

#define PHASE(SLOT, QC, KK, READA, STG_STMT, WAIT_STMT)                         \
  {                                                                             \
    const unsigned short* Ah = sm + (SLOT) * 32768 + wqr * 8192;                \
    const unsigned short* Bh = sm + (SLOT) * 32768 + 16384 + (QC) * 8192;       \
    const int ek = e0 ^ ((KK) * 32);                                            \
    if (READA) {                                                                \
      _Pragma("unroll")                                                         \
      for (int i = 0; i < 4; ++i)                                               \
        afr[i] = *(const short8*)(Ah + (pr * 64 + i * 16 + lr) * 64 + ek);      \
    }                                                                           \
    short8 bfr[4];                                                              \
    _Pragma("unroll")                                                           \
    for (int j = 0; j < 4; ++j)                                                 \
      bfr[j] = *(const short8*)(Bh + (pc * 64 + j * 16 + lr) * 64 + ek);        \
    STG_STMT;                                                                   \
    SBAR();                                                                     \
    __builtin_amdgcn_s_setprio(1);                                              \
    _Pragma("unroll")                                                           \
    for (int i = 0; i < 4; ++i)                                                 \
      _Pragma("unroll")                                                         \
      for (int j = 0; j < 4; ++j)                                               \
        acc[QC][i][j] = __builtin_amdgcn_mfma_f32_16x16x32_bf16(                \
            afr[i], bfr[j], acc[QC][i][j], 0, 0, 0);                            \
    __builtin_amdgcn_s_setprio(0);                                              \
    WAIT_STMT;                                                                  \
    SBAR();                                                                     \
  }

  // steady state: I = 0..30 (tiles a=2I in slot0, a+1 in slot1)
  for (int I = 0; I < 31; ++I) {
    const int a = 2 * I;
    PHASE(0, 0, 0, 1, STG(pA1, 1, 0, 1, a + 1), VMC(4));
    PHASE(0, 1, 0, 0, STG(pB0, 1, 1, 0, a + 1), ((void)0));
    PHASE(0, 0, 1, 1, STG(pB1, 1, 1, 1, a + 1), ((void)0));
    PHASE(0, 1, 1, 0, STG(pA0, 0, 0, 0, a + 2), VMC(4));
    PHASE(1, 0, 0, 1, STG(pA1, 0, 0, 1, a + 2), VMC(4));
    PHASE(1, 1, 0, 0, STG(pB0, 0, 1, 0, a + 2), ((void)0));
    PHASE(1, 0, 1, 1, STG(pB1, 0, 1, 1, a + 2), ((void)0));
    PHASE(1, 1, 1, 0, STG(pA0, 1, 0, 0, a + 3), VMC(4));
  }
  // tail I=31 (tiles 62, 63): stage only s1 remnants @63; drain 2 -> 0.
  PHASE(0, 0, 0, 1, STG(pA1, 1, 0, 1, 63), VMC(4));
  PHASE(0, 1, 0, 0, STG(pB0, 1, 1, 0, 63), ((void)0));
  PHASE(0, 0, 1, 1, STG(pB1, 1, 1, 1, 63), ((void)0));
  PHASE(0, 1, 1, 0, ((void)0), VMC(2));
  PHASE(1, 0, 0, 1, ((void)0), VMC(0));
  PHASE(1, 1, 0, 0, ((void)0), ((void)0));
  PHASE(1, 0, 1, 1, ((void)0), ((void)0));
  PHASE(1, 1, 1, 0, ((void)0), ((void)0));
#undef PHASE
#undef STG

  // epilogue: bias + store (C/D map: col=lr -> N, row=hi*4+e -> M)
  float bv[2][4];
#pragma unroll
  for (int qc = 0; qc < 2; ++qc)
#pragma unroll
    for (int j = 0; j < 4; ++j)
      bv[qc][j] = bias[n0 + qc * 128 + pc * 64 + j * 16 + lr];
  const int rowb = hi * 4;
#pragma unroll
  for (int qc = 0; qc < 2; ++qc)
#pragma unroll
    for (int i = 0; i < 4; ++i)
#pragma unroll
      for (int e = 0; e < 4; ++e) {
        int row = m0 + wqr * 128 + pr * 64 + i * 16 + rowb + e;
        float* orow = out + (size_t)row * 4096 + n0 + qc * 128 + pc * 64;
#pragma unroll
        for (int j = 0; j < 4; ++j) orow[j * 16 + lr] = acc[qc][i][j][e] + bv[qc][j];
      }
}

// ----------------------------------------------------------------- launch ----
extern "C" void kernel_launch(void* const* d_in, const int* in_sizes, int n_in,
                              void* d_out, int out_size, void* d_ws, size_t ws_size,
                              hipStream_t stream) {
  const float* x   = (const float*)d_in[0];
  const int* offs  = (const int*)d_in[1];
  const float* W   = (const float*)d_in[2];
  const float* b   = (const float*)d_in[3];
  const float* A   = (const float*)d_in[4];
  const float* Bw  = (const float*)d_in[5];
  float* out = (float*)d_out;

  char* ws = (char*)d_ws;
  unsigned short* xb  = (unsigned short*)ws;                 // 134,217,728 B
  unsigned short* Wb  = (unsigned short*)(ws + 134217728);   //  33,554,432 B
  unsigned short* Bwb = (unsigned short*)(ws + 167772160);   //     262,144 B
  unsigned short* T   = (unsigned short*)(ws + 168034304);   //   1,048,576 B

  hipFuncSetAttribute((const void*)gemm_kernel,
                      hipFuncAttributeMaxDynamicSharedMemorySize, 131072);

  cvt_lora_kernel<<<512, 256, 0, stream>>>(x, A, W, Bw, offs, xb, Wb, Bwb, T);
  gemm_kernel<<<1024, 512, 131072, stream>>>(xb, Wb, T, Bwb, b, out);
}